// Round 2
// baseline (27045.844 us; speedup 1.0000x reference)
//
#include <hip/hip_runtime.h>
#include <math.h>

// Problem constants
#define kB 256
#define kT 256
#define kD 512
#define kH 512
#define kO 256
#define kEPS 1e-5f

// Kernel config
#define NB 256        // persistent blocks == 256 CUs -> co-resident
#define BT 256        // threads per block (one per batch row)
#define HCOL 2        // kH / NB columns owned per block
#define KTILE 64      // k-tile for x staging
#define XSS 257       // padded LDS row stride

// barrier: 8 spread counters per phase, each on its own 64B line
#define BSLOT(p, j) ((((p) * 8) + (j)) * 16)
#define BARBYTES (513 * 8 * 64)

__device__ __forceinline__ void grid_barrier(int* bar, int phase) {
    __syncthreads();
    if (threadIdx.x == 0) {
        const int slot = blockIdx.x & 7;
        __hip_atomic_fetch_add(&bar[BSLOT(phase, slot)], 1, __ATOMIC_ACQ_REL, __HIP_MEMORY_SCOPE_AGENT);
        int s;
        do {
            s = 0;
#pragma unroll
            for (int j = 0; j < 8; ++j)
                s += __hip_atomic_load(&bar[BSLOT(phase, j)], __ATOMIC_ACQUIRE, __HIP_MEMORY_SCOPE_AGENT);
            if (s < NB) __builtin_amdgcn_s_sleep(1);
        } while (s < NB);
    }
    __syncthreads();
}

// block-wide BN stats: mean/rstd per owned column (thread = batch row)
__device__ __forceinline__ void block_bn_stats(const float acc[HCOL],
                                               float* sm, float* sr, float* red) {
    const int lane = threadIdx.x & 63;
    const int wid  = threadIdx.x >> 6;
#pragma unroll
    for (int c = 0; c < HCOL; ++c) {
        float s = acc[c];
        float q = acc[c] * acc[c];
#pragma unroll
        for (int off = 32; off > 0; off >>= 1) {
            s += __shfl_down(s, off, 64);
            q += __shfl_down(q, off, 64);
        }
        if (lane == 0) {
            red[(c * 4 + wid) * 2 + 0] = s;
            red[(c * 4 + wid) * 2 + 1] = q;
        }
    }
    __syncthreads();
    if (threadIdx.x < HCOL) {
        float s = 0.f, q = 0.f;
#pragma unroll
        for (int w = 0; w < 4; ++w) {
            s += red[(threadIdx.x * 4 + w) * 2 + 0];
            q += red[(threadIdx.x * 4 + w) * 2 + 1];
        }
        const float m   = s * (1.0f / kB);
        const float var = q * (1.0f / kB) - m * m;
        sm[threadIdx.x] = m;
        sr[threadIdx.x] = rsqrtf(var + kEPS);
    }
    __syncthreads();
}

__device__ __forceinline__ void cell_bn_tail(float acc[HCOL], float hprev[HCOL],
                                             const float pu[HCOL],
                                             const float pg1[HCOL], const float pbe1[HCOL],
                                             const float pg2[HCOL], const float pbe2[HCOL],
                                             float* sm, float* sr, float* red) {
    block_bn_stats(acc, sm, sr, red);
    float tmp[HCOL];
#pragma unroll
    for (int c = 0; c < HCOL; ++c) {
        const float zn = (acc[c] - sm[c]) * sr[c] * pg1[c] + pbe1[c];
        const float r  = zn + hprev[c] * pu[c];
        tmp[c] = r > 0.f ? r : 0.f;
    }
    block_bn_stats(tmp, sm, sr, red);
#pragma unroll
    for (int c = 0; c < HCOL; ++c)
        hprev[c] = (tmp[c] - sm[c]) * sr[c] * pg2[c] + pbe2[c];
}

// sequential GEMM: acc[c] += sum_k hw[k][b] * W[col0+c][k]
// 4 accumulator chains, 16 loads in flight (unroll 8 x 2 loads)
__device__ __forceinline__ void gemm_from_h(const float* __restrict__ hw,
                                            const float* __restrict__ W,
                                            int col0, int b, float acc[HCOL]) {
    const float* w0 = W + (size_t)(col0 + 0) * kH;
    const float* w1 = W + (size_t)(col0 + 1) * kH;
    float a0e = 0.f, a0o = 0.f, a1e = 0.f, a1o = 0.f;
#pragma unroll 8
    for (int k = 0; k < kH; k += 2) {
        const float v0 = hw[(k + 0) * kB + b];
        const float v1 = hw[(k + 1) * kB + b];
        a0e = fmaf(v0, w0[k + 0], a0e);
        a1e = fmaf(v0, w1[k + 0], a1e);
        a0o = fmaf(v1, w0[k + 1], a0o);
        a1o = fmaf(v1, w1[k + 1], a1o);
    }
    acc[0] += a0e + a0o;
    acc[1] += a1e + a1o;
}

__global__ __launch_bounds__(BT, 1) void indrnn_kernel(
    const float* __restrict__ x,
    const float* __restrict__ W0,  const float* __restrict__ b0,  const float* __restrict__ u0,
    const float* __restrict__ g10, const float* __restrict__ be10,
    const float* __restrict__ g20, const float* __restrict__ be20,
    const float* __restrict__ Wm,  const float* __restrict__ bm,  const float* __restrict__ um,
    const float* __restrict__ g1m, const float* __restrict__ be1m,
    const float* __restrict__ g2m, const float* __restrict__ be2m,
    const float* __restrict__ Wfc, const float* __restrict__ bfc,
    float* __restrict__ out,
    int* __restrict__ bar,
    float* __restrict__ h0w,   // [kH][kB] exchange (single-buffered; barrier-ordered)
    float* __restrict__ h1w,   // [kH][kB]
    float* __restrict__ h2n)   // [kB][kH]
{
    __shared__ float xs[KTILE * XSS];
    __shared__ float red[HCOL * 4 * 2];
    __shared__ float smean[HCOL], srstd[HCOL];
    __shared__ float hred[8];

    const int tid  = threadIdx.x;
    const int b    = tid;
    const int col0 = blockIdx.x * HCOL;

    float p_b0[HCOL], p_u0[HCOL], p_g10[HCOL], p_be10[HCOL], p_g20[HCOL], p_be20[HCOL];
    float p_bm[HCOL], p_um[HCOL], p_g1m[HCOL], p_be1m[HCOL], p_g2m[HCOL], p_be2m[HCOL];
#pragma unroll
    for (int c = 0; c < HCOL; ++c) {
        p_b0[c]  = b0[col0 + c];   p_u0[c]  = u0[col0 + c];
        p_g10[c] = g10[col0 + c];  p_be10[c] = be10[col0 + c];
        p_g20[c] = g20[col0 + c];  p_be20[c] = be20[col0 + c];
        p_bm[c]  = bm[col0 + c];   p_um[c]  = um[col0 + c];
        p_g1m[c] = g1m[col0 + c];  p_be1m[c] = be1m[col0 + c];
        p_g2m[c] = g2m[col0 + c];  p_be2m[c] = be2m[col0 + c];
    }

    float h0p[HCOL] = {0.f, 0.f};
    float h1p[HCOL] = {0.f, 0.f};
    float h2p[HCOL] = {0.f, 0.f};

    for (int t = 0; t < kT; ++t) {
        // ================= cell 0: z = x_t @ W0^T (x staged via LDS) =========
        float acc[HCOL];
#pragma unroll
        for (int c = 0; c < HCOL; ++c) acc[c] = p_b0[c];

        for (int kt = 0; kt < kD / KTILE; ++kt) {
            __syncthreads();
            const int l16 = tid & 15;
            const int rb  = tid >> 4;
#pragma unroll
            for (int pass = 0; pass < 16; ++pass) {
                const int row = rb + pass * 16;
                const float4 xv = *(const float4*)&x[((size_t)row * kT + t) * kD + kt * KTILE + l16 * 4];
                const int kk = l16 * 4;
                xs[(kk + 0) * XSS + row] = xv.x;
                xs[(kk + 1) * XSS + row] = xv.y;
                xs[(kk + 2) * XSS + row] = xv.z;
                xs[(kk + 3) * XSS + row] = xv.w;
            }
            __syncthreads();
            const float* w0p = W0 + (size_t)col0 * kD + kt * KTILE;
#pragma unroll 8
            for (int kl = 0; kl < KTILE; ++kl) {
                const float v = xs[kl * XSS + b];
#pragma unroll
                for (int c = 0; c < HCOL; ++c)
                    acc[c] = fmaf(v, w0p[(size_t)c * kD + kl], acc[c]);
            }
        }
        cell_bn_tail(acc, h0p, p_u0, p_g10, p_be10, p_g20, p_be20, smean, srstd, red);
#pragma unroll
        for (int c = 0; c < HCOL; ++c) h0w[(col0 + c) * kB + b] = h0p[c];
        grid_barrier(bar, 2 * t);

        // ================= cell 1: z = h0 @ Wm^T =============================
#pragma unroll
        for (int c = 0; c < HCOL; ++c) acc[c] = p_bm[c];
        gemm_from_h(h0w, Wm, col0, b, acc);
        cell_bn_tail(acc, h1p, p_um, p_g1m, p_be1m, p_g2m, p_be2m, smean, srstd, red);
#pragma unroll
        for (int c = 0; c < HCOL; ++c) h1w[(col0 + c) * kB + b] = h1p[c];
        grid_barrier(bar, 2 * t + 1);

        // ================= cell 2: z = h1 @ Wm^T =============================
#pragma unroll
        for (int c = 0; c < HCOL; ++c) acc[c] = p_bm[c];
        gemm_from_h(h1w, Wm, col0, b, acc);
        cell_bn_tail(acc, h2p, p_um, p_g1m, p_be1m, p_g2m, p_be2m, smean, srstd, red);
        if (t == kT - 1) {
#pragma unroll
            for (int c = 0; c < HCOL; ++c) h2n[(size_t)b * kH + col0 + c] = h2p[c];
        }
    }

    grid_barrier(bar, 2 * kT);   // h2n fully written

    // ================= head: 1 row per block, logits + log_softmax ===========
    {
        const int row = blockIdx.x;
        __syncthreads();
        xs[tid]       = h2n[(size_t)row * kH + tid];
        xs[tid + 256] = h2n[(size_t)row * kH + 256 + tid];
        __syncthreads();

        const int o = tid;
        float dot = bfc[o];
        const float* wf = Wfc + (size_t)o * kH;
#pragma unroll 8
        for (int h = 0; h < kH; ++h) dot = fmaf(xs[h], wf[h], dot);

        const int lane = tid & 63, wid = tid >> 6;
        float m = dot;
#pragma unroll
        for (int off = 32; off > 0; off >>= 1) m = fmaxf(m, __shfl_down(m, off, 64));
        if (lane == 0) hred[wid] = m;
        __syncthreads();
        const float M = fmaxf(fmaxf(hred[0], hred[1]), fmaxf(hred[2], hred[3]));
        float e = expf(dot - M);
        float s = e;
#pragma unroll
        for (int off = 32; off > 0; off >>= 1) s += __shfl_down(s, off, 64);
        if (lane == 0) hred[4 + wid] = s;
        __syncthreads();
        const float S = hred[4] + hred[5] + hred[6] + hred[7];
        out[(size_t)row * kO + o] = dot - M - logf(S);
    }
}

extern "C" void kernel_launch(void* const* d_in, const int* in_sizes, int n_in,
                              void* d_out, int out_size, void* d_ws, size_t ws_size,
                              hipStream_t stream) {
    const float* x    = (const float*)d_in[0];
    const float* W0   = (const float*)d_in[1];
    const float* b0   = (const float*)d_in[2];
    const float* u0   = (const float*)d_in[3];
    const float* g10  = (const float*)d_in[4];
    const float* be10 = (const float*)d_in[5];
    const float* g20  = (const float*)d_in[6];
    const float* be20 = (const float*)d_in[7];
    const float* Wm   = (const float*)d_in[8];
    const float* bm   = (const float*)d_in[9];
    const float* um   = (const float*)d_in[10];
    const float* g1m  = (const float*)d_in[11];
    const float* be1m = (const float*)d_in[12];
    const float* g2m  = (const float*)d_in[13];
    const float* be2m = (const float*)d_in[14];
    const float* Wfc  = (const float*)d_in[15];
    const float* bfc  = (const float*)d_in[16];
    float* out = (float*)d_out;

    char* ws = (char*)d_ws;
    int*   bar = (int*)ws;                         // 512 KB barrier region
    float* h0w = (float*)(ws + 524288);            // 512 KB
    float* h1w = (float*)(ws + 1048576);           // 512 KB
    float* h2n = (float*)(ws + 1572864);           // 512 KB

    hipMemsetAsync(d_ws, 0, BARBYTES, stream);     // zero barrier counters

    hipLaunchKernelGGL(indrnn_kernel, dim3(NB), dim3(BT), 0, stream,
                       x, W0, b0, u0, g10, be10, g20, be20,
                       Wm, bm, um, g1m, be1m, g2m, be2m, Wfc, bfc,
                       out, bar, h0w, h1w, h2n);
}

// Round 5
// 9372.980 us; speedup vs baseline: 2.8855x; 2.8855x over previous
//
#include <hip/hip_runtime.h>
#include <math.h>

// Problem: B=256, T=256, D=H=512, O=256, L=3 (cell0 + 2 shared middle cells)
#define kT 256
#define kEPS 1e-5f
#define NB 32     // 32 persistent blocks, 16 H-columns each, full batch per block
#define BT 256    // 4 waves

typedef __attribute__((ext_vector_type(8))) _Float16 half8;  // 8 fp16 (4 VGPRs)
typedef __attribute__((ext_vector_type(4))) float f32x4;

// barrier: 4 spread counters per phase, 64B apart; phase-indexed (memset at launch)
#define BSLOT(p, j) (((p)*4 + (j)) * 16)
#define BARBYTES (320 * 4 * 64)

// pack v as {hi=fp16(v)} | {lo=fp16(v-hi)}<<16 : 22-bit effective mantissa in 4B
__device__ __forceinline__ unsigned packhl(float f) {
    _Float16 hi = (_Float16)f;
    _Float16 lo = (_Float16)(f - (float)hi);
    unsigned short uh, ul;
    __builtin_memcpy(&uh, &hi, 2);
    __builtin_memcpy(&ul, &lo, 2);
    return (unsigned)uh | ((unsigned)ul << 16);
}

// Relaxed-atomic barrier: exchange uses sc1 write-through stores (no wbl2);
// single acquire fence (L1/L2 invalidate) on exit.
__device__ __forceinline__ void grid_barrier(int* bar, int phase) {
    __syncthreads();
    if (threadIdx.x == 0) {
        const int slot = blockIdx.x & 3;
        __hip_atomic_fetch_add(&bar[BSLOT(phase, slot)], 1, __ATOMIC_RELAXED, __HIP_MEMORY_SCOPE_AGENT);
        int s;
        do {
            s = 0;
#pragma unroll
            for (int j = 0; j < 4; ++j)
                s += __hip_atomic_load(&bar[BSLOT(phase, j)], __ATOMIC_RELAXED, __HIP_MEMORY_SCOPE_AGENT);
            if (s < NB) __builtin_amdgcn_s_sleep(2);
        } while (s < NB);
    }
    __syncthreads();
    __builtin_amdgcn_fence(__ATOMIC_ACQUIRE, "agent");
}

// BN stats over batch (N) for the block's 16 columns (M), data in MFMA C/D layout:
// lane (q=lane>>4, c=lane&15), wave w: holds m=q*4+r (r=reg), n=w*64+nt*16+c.
__device__ __forceinline__ void bn_stats(const f32x4 v[4], float* bnS, float* bnQ,
                                         float* bnM, float* bnR, int q, int c, int w, int tid) {
    float s[4], sq[4];
#pragma unroll
    for (int r = 0; r < 4; ++r) {
        s[r] = 0.f; sq[r] = 0.f;
#pragma unroll
        for (int nt = 0; nt < 4; ++nt) { float t = v[nt][r]; s[r] += t; sq[r] += t * t; }
    }
#pragma unroll
    for (int mk = 1; mk < 16; mk <<= 1) {
#pragma unroll
        for (int r = 0; r < 4; ++r) {
            s[r]  += __shfl_xor(s[r],  mk, 64);
            sq[r] += __shfl_xor(sq[r], mk, 64);
        }
    }
    if (c == 0) {
#pragma unroll
        for (int r = 0; r < 4; ++r) { bnS[(q*4+r)*4 + w] = s[r]; bnQ[(q*4+r)*4 + w] = sq[r]; }
    }
    __syncthreads();
    if (tid < 16) {
        float S = bnS[tid*4] + bnS[tid*4+1] + bnS[tid*4+2] + bnS[tid*4+3];
        float Q = bnQ[tid*4] + bnQ[tid*4+1] + bnQ[tid*4+2] + bnQ[tid*4+3];
        float mn  = S * (1.f/256.f);
        float var = Q * (1.f/256.f) - mn*mn;
        bnM[tid] = mn; bnR[tid] = rsqrtf(var + kEPS);
    }
    __syncthreads();
}

// pp: [0..15]=u, [16..31]=g1, [32..47]=be1, [48..63]=g2, [64..79]=be2
// (biases b0/bm dropped: they cancel inside training-mode BN)
__device__ __forceinline__ void bn_tail(const f32x4 acc[4], f32x4 h[4], const float* pp,
                                        float* bnS, float* bnQ, float* bnM, float* bnR,
                                        int q, int c, int w, int tid) {
    bn_stats(acc, bnS, bnQ, bnM, bnR, q, c, w, tid);
    f32x4 tmp[4];
    float mn[4], rs[4];
#pragma unroll
    for (int r = 0; r < 4; ++r) { mn[r] = bnM[q*4+r]; rs[r] = bnR[q*4+r]; }
#pragma unroll
    for (int nt = 0; nt < 4; ++nt)
#pragma unroll
        for (int r = 0; r < 4; ++r) {
            int m = q*4 + r;
            float zn = (acc[nt][r] - mn[r]) * rs[r] * pp[16+m] + pp[32+m];
            float rl = zn + h[nt][r] * pp[m];
            tmp[nt][r] = rl > 0.f ? rl : 0.f;
        }
    bn_stats(tmp, bnS, bnQ, bnM, bnR, q, c, w, tid);
#pragma unroll
    for (int r = 0; r < 4; ++r) { mn[r] = bnM[q*4+r]; rs[r] = bnR[q*4+r]; }
#pragma unroll
    for (int nt = 0; nt < 4; ++nt)
#pragma unroll
        for (int r = 0; r < 4; ++r) {
            int m = q*4 + r;
            h[nt][r] = (tmp[nt][r] - mn[r]) * rs[r] * pp[48+m] + pp[64+m];
        }
}

// load 8 packed words (32B), split into hi/lo half8, 3 MFMAs into acc
__device__ __forceinline__ void mfma3(const unsigned* __restrict__ p,
                                      half8 ahi, half8 alo, f32x4& acc) {
    uint4 A = *(const uint4*)p;
    uint4 B = *(const uint4*)(p + 4);
    unsigned hh[4], ll[4];
    hh[0] = __builtin_amdgcn_perm(A.y, A.x, 0x05040100u);
    ll[0] = __builtin_amdgcn_perm(A.y, A.x, 0x07060302u);
    hh[1] = __builtin_amdgcn_perm(A.w, A.z, 0x05040100u);
    ll[1] = __builtin_amdgcn_perm(A.w, A.z, 0x07060302u);
    hh[2] = __builtin_amdgcn_perm(B.y, B.x, 0x05040100u);
    ll[2] = __builtin_amdgcn_perm(B.y, B.x, 0x07060302u);
    hh[3] = __builtin_amdgcn_perm(B.w, B.z, 0x05040100u);
    ll[3] = __builtin_amdgcn_perm(B.w, B.z, 0x07060302u);
    half8 bhi, blo;
    __builtin_memcpy(&bhi, hh, 16);
    __builtin_memcpy(&blo, ll, 16);
    acc = __builtin_amdgcn_mfma_f32_16x16x32_f16(ahi, bhi, acc, 0, 0, 0);
    acc = __builtin_amdgcn_mfma_f32_16x16x32_f16(ahi, blo, acc, 0, 0, 0);
    acc = __builtin_amdgcn_mfma_f32_16x16x32_f16(alo, bhi, acc, 0, 0, 0);
}

// K=512 GEMM: A hi/lo from LDS planes, B hi/lo packed words. KSTR in 32-bit words.
template<int KSTR>
__device__ __forceinline__ void gemm_hl(const unsigned* __restrict__ p0,
                                        const unsigned* __restrict__ p1,
                                        const unsigned* __restrict__ p2,
                                        const unsigned* __restrict__ p3,
                                        const unsigned short* __restrict__ waHi,
                                        const unsigned short* __restrict__ waLo,
                                        f32x4 acc[4]) {
#pragma unroll
    for (int ks = 0; ks < 16; ++ks) {
        half8 ahi = *(const half8*)(waHi + ks*512);
        half8 alo = *(const half8*)(waLo + ks*512);
        mfma3(p0 + (long long)ks*KSTR, ahi, alo, acc[0]);
        mfma3(p1 + (long long)ks*KSTR, ahi, alo, acc[1]);
        mfma3(p2 + (long long)ks*KSTR, ahi, alo, acc[2]);
        mfma3(p3 + (long long)ks*KSTR, ahi, alo, acc[3]);
    }
}

// write h (C/D layout) to exchange [K/8][B][8]packed-words via sc1 8B atomic stores
__device__ __forceinline__ void store_h(unsigned* hp, const f32x4 h[4],
                                        int c0, int q, int c, int w) {
    unsigned long long* hpu = (unsigned long long*)hp;
    const int gbase = ((c0 >> 3) + (q >> 1)) * 256;
    const int sub = (q & 1) * 2;
#pragma unroll
    for (int nt = 0; nt < 4; ++nt) {
        int b = w*64 + nt*16 + c;
        unsigned w0 = packhl(h[nt][0]), w1 = packhl(h[nt][1]);
        unsigned w2 = packhl(h[nt][2]), w3 = packhl(h[nt][3]);
        unsigned long long v0 = (unsigned long long)w0 | ((unsigned long long)w1 << 32);
        unsigned long long v1 = (unsigned long long)w2 | ((unsigned long long)w3 << 32);
        long long idx = (long long)(gbase + b)*4 + sub;
        __hip_atomic_store(hpu + idx,     v0, __ATOMIC_RELAXED, __HIP_MEMORY_SCOPE_AGENT);
        __hip_atomic_store(hpu + idx + 1, v1, __ATOMIC_RELAXED, __HIP_MEMORY_SCOPE_AGENT);
    }
}

// cell with B from packed x: z = x_t @ W0^T
__device__ __forceinline__ void cell_x(const unsigned* __restrict__ xw, int t,
                                       const unsigned short* waHi, const unsigned short* waLo,
                                       f32x4 h[4], const float* pp,
                                       float* bnS, float* bnQ, float* bnM, float* bnR,
                                       unsigned* hpdst, int c0, int q, int c, int w, int tid,
                                       long long nb) {
    f32x4 acc[4] = {};
    const unsigned* b0 = xw + nb*131072LL + (long long)t*512 + q*8;
    gemm_hl<32>(b0, b0 + 2097152LL, b0 + 4194304LL, b0 + 6291456LL, waHi, waLo, acc);
    bn_tail(acc, h, pp, bnS, bnQ, bnM, bnR, q, c, w, tid);
    store_h(hpdst, h, c0, q, c, w);
}

// cell with B from exchange: z = hprev @ Wm^T
__device__ __forceinline__ void cell_h(const unsigned* __restrict__ hw,
                                       const unsigned short* waHi, const unsigned short* waLo,
                                       f32x4 h[4], const float* pp,
                                       float* bnS, float* bnQ, float* bnM, float* bnR,
                                       unsigned* hpdst, int c0, int q, int c, int w, int tid,
                                       int nbase) {
    f32x4 acc[4] = {};
    const unsigned* b0 = hw + (q*256 + nbase)*8;
    gemm_hl<8192>(b0, b0 + 128, b0 + 256, b0 + 384, waHi, waLo, acc);
    bn_tail(acc, h, pp, bnS, bnQ, bnM, bnR, q, c, w, tid);
    if (hpdst) store_h(hpdst, h, c0, q, c, w);
}

__global__ __launch_bounds__(BT, 1) void indrnn(
    float* __restrict__ x,                       // overwritten in place with packed hi/lo
    const float* __restrict__ W0, const float* __restrict__ u0,
    const float* __restrict__ g10, const float* __restrict__ be10,
    const float* __restrict__ g20, const float* __restrict__ be20,
    const float* __restrict__ Wm, const float* __restrict__ um,
    const float* __restrict__ g1m, const float* __restrict__ be1m,
    const float* __restrict__ g2m, const float* __restrict__ be2m,
    const float* __restrict__ Wfc, const float* __restrict__ bfc,
    float* __restrict__ out, int* __restrict__ bar,
    unsigned* __restrict__ hpws,                 // hp0[2],hp1[2]: 4 x 131072 words
    float* __restrict__ h2n)                     // [256][512] fp32
{
    __shared__ __align__(16) unsigned short WAhi_m[8192];  // Wm A-frags hi (head reuses)
    __shared__ __align__(16) unsigned short WAlo_m[8192];
    __shared__ __align__(16) unsigned short WAhi_0[8192];  // W0 A-frags hi
    __shared__ __align__(16) unsigned short WAlo_0[8192];
    __shared__ float bnS[64], bnQ[64], bnM[16], bnR[16];
    __shared__ float prm[160];
    __shared__ float hred[8];

    const int tid  = threadIdx.x;
    const int blk  = blockIdx.x;
    const int gid  = blk*BT + tid;
    const int lane = tid & 63;
    const int w    = tid >> 6;
    const int q    = lane >> 4;
    const int c    = lane & 15;
    const int c0   = blk * 16;
    const int nbase = w*64 + c;

    // ---- stage weight A-fragments into LDS, hi/lo planes ----
    for (int e = tid; e < 1024; e += BT) {
        int ks = e >> 6, l = e & 63;
        int cc = l & 15, qq = l >> 4;
        const float* sm = Wm + (size_t)(c0+cc)*512 + ks*32 + qq*8;
        const float* s0 = W0 + (size_t)(c0+cc)*512 + ks*32 + qq*8;
        unsigned short mh[8], ml[8], zh[8], zl[8];
#pragma unroll
        for (int j = 0; j < 8; ++j) {
            unsigned pm = packhl(sm[j]);
            unsigned p0 = packhl(s0[j]);
            mh[j] = (unsigned short)pm; ml[j] = (unsigned short)(pm >> 16);
            zh[j] = (unsigned short)p0; zl[j] = (unsigned short)(p0 >> 16);
        }
        __builtin_memcpy(&WAhi_m[e*8], mh, 16);
        __builtin_memcpy(&WAlo_m[e*8], ml, 16);
        __builtin_memcpy(&WAhi_0[e*8], zh, 16);
        __builtin_memcpy(&WAlo_0[e*8], zl, 16);
    }
    if (tid < 16) {
        prm[tid]      = u0[c0+tid];   prm[16+tid]  = g10[c0+tid];  prm[32+tid]  = be10[c0+tid];
        prm[48+tid]   = g20[c0+tid];  prm[64+tid]  = be20[c0+tid];
        prm[80+tid]   = um[c0+tid];   prm[96+tid]  = g1m[c0+tid];  prm[112+tid] = be1m[c0+tid];
        prm[128+tid]  = g2m[c0+tid];  prm[144+tid] = be2m[c0+tid];
    }

    // ---- x fp32 -> packed hi/lo, in place word-for-word (no cross-thread hazard) ----
    unsigned* xw = (unsigned*)x;
    for (long long i = (long long)gid*4; i < 33554432LL; i += 32768LL) {
        float4 v = *(const float4*)(x + i);
        uint4 pw;
        pw.x = packhl(v.x); pw.y = packhl(v.y); pw.z = packhl(v.z); pw.w = packhl(v.w);
        *(uint4*)(xw + i) = pw;
    }
    __builtin_amdgcn_fence(__ATOMIC_RELEASE, "agent");   // one wbl2, once
    grid_barrier(bar, 0);

    // ---- sequential recurrence: 256 steps x 3 cells, ONE grid barrier/step ----
    // order: cell1(t); cell0(t+1); barrier; cell2(t) — parity double-buffering
    // makes every RAW/WAR pair barrier-separated.
    f32x4 h0[4] = {}, h1[4] = {}, h2[4] = {};

    cell_x(xw, 0, WAhi_0 + lane*8, WAlo_0 + lane*8, h0, prm,
           bnS, bnQ, bnM, bnR, hpws + 0, c0, q, c, w, tid, nbase);
    grid_barrier(bar, 1);

    for (int t = 0; t < kT; ++t) {
        const int par = t & 1;
        unsigned* hp0r = hpws + par*131072;
        unsigned* hp0w = hpws + (par^1)*131072;
        unsigned* hp1r = hpws + 262144 + par*131072;

        cell_h(hp0r, WAhi_m + lane*8, WAlo_m + lane*8, h1, prm + 80,
               bnS, bnQ, bnM, bnR, hp1r, c0, q, c, w, tid, nbase);
        if (t + 1 < kT)
            cell_x(xw, t + 1, WAhi_0 + lane*8, WAlo_0 + lane*8, h0, prm,
                   bnS, bnQ, bnM, bnR, hp0w, c0, q, c, w, tid, nbase);
        grid_barrier(bar, 2 + t);
        cell_h(hp1r, WAhi_m + lane*8, WAlo_m + lane*8, h2, prm + 80,
               bnS, bnQ, bnM, bnR, (unsigned*)nullptr, c0, q, c, w, tid, nbase);
    }

    // ---- final h2 -> h2n (fp32, coherent 8B stores) ----
    {
        unsigned long long* h2u = (unsigned long long*)h2n;
#pragma unroll
        for (int nt = 0; nt < 4; ++nt) {
            int b = nbase + nt*16;
#pragma unroll
            for (int pr = 0; pr < 2; ++pr) {
                float fv[2] = { h2[nt][pr*2], h2[nt][pr*2+1] };
                unsigned long long val;
                __builtin_memcpy(&val, fv, 8);
                __hip_atomic_store(h2u + (((size_t)b*512 + c0 + q*4) >> 1) + pr, val,
                                   __ATOMIC_RELAXED, __HIP_MEMORY_SCOPE_AGENT);
            }
        }
    }
    grid_barrier(bar, 2 + kT);

    // ---- head: 8 batch rows per block; logits + log_softmax ----
    {
        float* hs = (float*)WAhi_m;   // reuse 16KB LDS: 8 rows x 512
        __syncthreads();
#pragma unroll
        for (int i = 0; i < 4; ++i)
            ((float4*)hs)[tid + i*256] = ((const float4*)(h2n + (size_t)blk*4096))[tid + i*256];
        __syncthreads();

        const int row = tid >> 5;            // 0..7
        const int o0  = (tid & 31) * 8;      // 8 outputs per thread
        const float* hrow = hs + row*512;
        float dots[8];
#pragma unroll
        for (int oo = 0; oo < 8; ++oo) {
            const float* wf = Wfc + (size_t)(o0+oo)*512;
            float d = 0.f;
#pragma unroll 8
            for (int h = 0; h < 512; h += 4) {
                float4 wv = *(const float4*)(wf + h);
                d += hrow[h]*wv.x + hrow[h+1]*wv.y + hrow[h+2]*wv.z + hrow[h+3]*wv.w;
            }
            dots[oo] = d + bfc[o0+oo];
        }
        float M = dots[0];
#pragma unroll
        for (int oo = 1; oo < 8; ++oo) M = fmaxf(M, dots[oo]);
#pragma unroll
        for (int mk = 1; mk < 32; mk <<= 1) M = fmaxf(M, __shfl_xor(M, mk, 64));
        float S = 0.f;
#pragma unroll
        for (int oo = 0; oo < 8; ++oo) S += expf(dots[oo] - M);
#pragma unroll
        for (int mk = 1; mk < 32; mk <<= 1) S += __shfl_xor(S, mk, 64);
        float lse = M + logf(S);
#pragma unroll
        for (int oo = 0; oo < 8; ++oo)
            out[(size_t)(blk*8 + row)*256 + o0 + oo] = dots[oo] - lse;
    }
    (void)hred;
}

extern "C" void kernel_launch(void* const* d_in, const int* in_sizes, int n_in,
                              void* d_out, int out_size, void* d_ws, size_t ws_size,
                              hipStream_t stream) {
    float* x          = (float*)d_in[0];          // mutated; harness restores pristine
    const float* W0   = (const float*)d_in[1];
    const float* u0   = (const float*)d_in[3];
    const float* g10  = (const float*)d_in[4];
    const float* be10 = (const float*)d_in[5];
    const float* g20  = (const float*)d_in[6];
    const float* be20 = (const float*)d_in[7];
    const float* Wm   = (const float*)d_in[8];
    const float* um   = (const float*)d_in[10];
    const float* g1m  = (const float*)d_in[11];
    const float* be1m = (const float*)d_in[12];
    const float* g2m  = (const float*)d_in[13];
    const float* be2m = (const float*)d_in[14];
    const float* Wfc  = (const float*)d_in[15];
    const float* bfc  = (const float*)d_in[16];
    // b0 (d_in[2]) / bm (d_in[9]) cancel inside training-mode BatchNorm -> unused
    float* out = (float*)d_out;

    char* ws = (char*)d_ws;
    int* bar        = (int*)ws;                       // 128KB barrier phases
    unsigned* hpws  = (unsigned*)(ws + 131072);       // 4 x 512KB exchange (packed hi/lo)
    float* h2n      = (float*)(ws + 131072 + 2097152);// 512KB

    hipMemsetAsync(d_ws, 0, BARBYTES, stream);

    hipLaunchKernelGGL(indrnn, dim3(NB), dim3(BT), 0, stream,
                       x, W0, u0, g10, be10, g20, be20,
                       Wm, um, g1m, be1m, g2m, be2m, Wfc, bfc,
                       out, bar, hpws, h2n);
}

// Round 6
// 7643.892 us; speedup vs baseline: 3.5382x; 1.2262x over previous
//
#include <hip/hip_runtime.h>
#include <math.h>

// Problem: B=256, T=256, D=H=512, O=256, L=3 (cell0 + 2 shared middle cells)
#define kT 256
#define kEPS 1e-5f
#define NB 32      // persistent blocks, 16 H-columns each, full batch per block
#define BT 1024    // 16 waves -> 4 waves/SIMD TLP on each of the 32 CUs

typedef __attribute__((ext_vector_type(8))) _Float16 half8;  // 8 fp16 (4 VGPRs)
typedef __attribute__((ext_vector_type(4))) float f32x4;

// barrier: 4 spread counters per phase, 64B apart; phase-indexed (memset at launch)
#define BSLOT(p, j) (((p)*4 + (j)) * 16)
#define BARBYTES (260 * 4 * 64)

// pack v as {hi=fp16(v)} | {lo=fp16(v-hi)}<<16 : 22-bit effective mantissa in 4B
__device__ __forceinline__ unsigned packhl(float f) {
    _Float16 hi = (_Float16)f;
    _Float16 lo = (_Float16)(f - (float)hi);
    unsigned short uh, ul;
    __builtin_memcpy(&uh, &hi, 2);
    __builtin_memcpy(&ul, &lo, 2);
    return (unsigned)uh | ((unsigned)ul << 16);
}

__device__ __forceinline__ float unpackhl(unsigned wd) {
    unsigned short uh = (unsigned short)wd, ul = (unsigned short)(wd >> 16);
    _Float16 hi, lo;
    __builtin_memcpy(&hi, &uh, 2);
    __builtin_memcpy(&lo, &ul, 2);
    return (float)hi + (float)lo;
}

// split 8 packed words (two uint4) into hi/lo half8 fragments (8 v_perm_b32)
__device__ __forceinline__ void split32(uint4 A, uint4 B, half8& hi, half8& lo) {
    unsigned hh[4], ll[4];
    hh[0] = __builtin_amdgcn_perm(A.y, A.x, 0x05040100u);
    ll[0] = __builtin_amdgcn_perm(A.y, A.x, 0x07060302u);
    hh[1] = __builtin_amdgcn_perm(A.w, A.z, 0x05040100u);
    ll[1] = __builtin_amdgcn_perm(A.w, A.z, 0x07060302u);
    hh[2] = __builtin_amdgcn_perm(B.y, B.x, 0x05040100u);
    ll[2] = __builtin_amdgcn_perm(B.y, B.x, 0x07060302u);
    hh[3] = __builtin_amdgcn_perm(B.w, B.z, 0x05040100u);
    ll[3] = __builtin_amdgcn_perm(B.w, B.z, 0x07060302u);
    __builtin_memcpy(&hi, hh, 16);
    __builtin_memcpy(&lo, ll, 16);
}

// 3-term hi/lo MFMA: acc += A*B with ~22-bit operand precision
__device__ __forceinline__ void mfma3p(const unsigned* __restrict__ p,
                                       half8 ahi, half8 alo, f32x4& acc) {
    half8 bhi, blo;
    split32(*(const uint4*)p, *(const uint4*)(p + 4), bhi, blo);
    acc = __builtin_amdgcn_mfma_f32_16x16x32_f16(ahi, bhi, acc, 0, 0, 0);
    acc = __builtin_amdgcn_mfma_f32_16x16x32_f16(ahi, blo, acc, 0, 0, 0);
    acc = __builtin_amdgcn_mfma_f32_16x16x32_f16(alo, bhi, acc, 0, 0, 0);
}

// ============================ kernel 1: pack W0 ============================
__global__ __launch_bounds__(256) void w0pack(const float* __restrict__ W0,
                                              unsigned* __restrict__ W0p) {
    const int i4 = (blockIdx.x * 256 + threadIdx.x) * 4;   // 262144 words total
    float4 v = *(const float4*)(W0 + i4);
    uint4 pw;
    pw.x = packhl(v.x); pw.y = packhl(v.y); pw.z = packhl(v.z); pw.w = packhl(v.w);
    *(uint4*)(W0p + i4) = pw;
}

// ================= kernel 2: z0 = x @ W0^T, packed, IN PLACE over x ========
// 2048 blocks x 1024 thr; block owns 32 bt-rows (bt = b*256+t), all 512 m.
// x rows staged+converted to LDS first -> overwrite is block-local-safe.
#define ZROWS 32
#define XSTR 516   // padded word stride: c*516 % 32 banks -> 2-way only (free)
__global__ __launch_bounds__(1024, 4) void zgemm(float* __restrict__ x,
                                                 const unsigned* __restrict__ W0p) {
    __shared__ unsigned xs[ZROWS * XSTR];
    const int tid = threadIdx.x;
    const long long r0 = (long long)blockIdx.x * ZROWS;

    {   // stage 32 rows x 512 floats -> packed words in LDS
        const int row = tid >> 5;
        const int k0 = (tid & 31) * 16;
        const float* src = x + (r0 + row) * 512 + k0;
        unsigned* dst = xs + row * XSTR + k0;
#pragma unroll
        for (int i = 0; i < 4; ++i) {
            float4 v = *(const float4*)(src + i * 4);
            uint4 pw;
            pw.x = packhl(v.x); pw.y = packhl(v.y); pw.z = packhl(v.z); pw.w = packhl(v.w);
            *(uint4*)(dst + i * 4) = pw;
        }
    }
    __syncthreads();

    const int w = tid >> 6, lane = tid & 63, q = lane >> 4, c = lane & 15;
    const int mt0 = w * 2;                      // wave covers m-tiles mt0, mt0+1
    f32x4 acc[2][2] = {};                       // [m-tile][row-subtile]
#pragma unroll
    for (int ks = 0; ks < 16; ++ks) {
        half8 ahi[2], alo[2], bhi[2], blo[2];
#pragma unroll
        for (int m = 0; m < 2; ++m) {
            const unsigned* ap = W0p + ((mt0 + m) * 16 + c) * 512 + ks * 32 + q * 8;
            split32(*(const uint4*)ap, *(const uint4*)(ap + 4), ahi[m], alo[m]);
        }
#pragma unroll
        for (int s = 0; s < 2; ++s) {
            const unsigned* bp = xs + (s * 16 + c) * XSTR + ks * 32 + q * 8;
            split32(*(const uint4*)bp, *(const uint4*)(bp + 4), bhi[s], blo[s]);
        }
#pragma unroll
        for (int m = 0; m < 2; ++m)
#pragma unroll
            for (int s = 0; s < 2; ++s) {
                acc[m][s] = __builtin_amdgcn_mfma_f32_16x16x32_f16(ahi[m], bhi[s], acc[m][s], 0, 0, 0);
                acc[m][s] = __builtin_amdgcn_mfma_f32_16x16x32_f16(ahi[m], blo[s], acc[m][s], 0, 0, 0);
                acc[m][s] = __builtin_amdgcn_mfma_f32_16x16x32_f16(alo[m], bhi[s], acc[m][s], 0, 0, 0);
            }
    }
    // store z0 packed at [bt][m] (same addresses x occupied; reads all done)
    unsigned* zw = (unsigned*)x;
#pragma unroll
    for (int m = 0; m < 2; ++m)
#pragma unroll
        for (int s = 0; s < 2; ++s) {
            unsigned* zp = zw + (r0 + s * 16 + c) * 512 + (mt0 + m) * 16 + q * 4;
            uint4 pw;
            pw.x = packhl(acc[m][s][0]); pw.y = packhl(acc[m][s][1]);
            pw.z = packhl(acc[m][s][2]); pw.w = packhl(acc[m][s][3]);
            *(uint4*)zp = pw;
        }
}

// ======================= persistent sequential kernel ======================
__device__ __forceinline__ void grid_barrier(int* bar, int phase) {
    __syncthreads();
    if (threadIdx.x == 0) {
        const int slot = blockIdx.x & 3;
        __hip_atomic_fetch_add(&bar[BSLOT(phase, slot)], 1, __ATOMIC_RELAXED, __HIP_MEMORY_SCOPE_AGENT);
        int s;
        do {
            s = 0;
#pragma unroll
            for (int j = 0; j < 4; ++j)
                s += __hip_atomic_load(&bar[BSLOT(phase, j)], __ATOMIC_RELAXED, __HIP_MEMORY_SCOPE_AGENT);
            if (s < NB) __builtin_amdgcn_s_sleep(2);
        } while (s < NB);
    }
    __syncthreads();
    __builtin_amdgcn_fence(__ATOMIC_ACQUIRE, "agent");
}

// BN stats over batch for the block's 16 columns. C/D layout, 16 waves:
// lane (q,c), wave w holds m=q*4+r, n=w*16+c.
__device__ __forceinline__ void bn_stats1(const f32x4 v, float* bnS, float* bnQ,
                                          float* bnM, float* bnR, int q, int c, int w, int tid) {
    float s[4], sq[4];
#pragma unroll
    for (int r = 0; r < 4; ++r) { s[r] = v[r]; sq[r] = v[r] * v[r]; }
#pragma unroll
    for (int mk = 1; mk < 16; mk <<= 1) {
#pragma unroll
        for (int r = 0; r < 4; ++r) {
            s[r]  += __shfl_xor(s[r],  mk, 64);
            sq[r] += __shfl_xor(sq[r], mk, 64);
        }
    }
    if (c == 0) {
#pragma unroll
        for (int r = 0; r < 4; ++r) { bnS[(q*4+r)*16 + w] = s[r]; bnQ[(q*4+r)*16 + w] = sq[r]; }
    }
    __syncthreads();
    if (tid < 16) {
        float S = 0.f, Q = 0.f;
#pragma unroll
        for (int j = 0; j < 16; ++j) { S += bnS[tid*16 + j]; Q += bnQ[tid*16 + j]; }
        float mn  = S * (1.f/256.f);
        float var = Q * (1.f/256.f) - mn * mn;
        bnM[tid] = mn; bnR[tid] = rsqrtf(var + kEPS);
    }
    __syncthreads();
}

// pp: [0..15]=u, [16..31]=g1, [32..47]=be1, [48..63]=g2, [64..79]=be2
__device__ __forceinline__ void bn_tail1(const f32x4 acc, f32x4& h, const float* pp,
                                         float* bnS, float* bnQ, float* bnM, float* bnR,
                                         int q, int c, int w, int tid) {
    bn_stats1(acc, bnS, bnQ, bnM, bnR, q, c, w, tid);
    f32x4 tmp;
#pragma unroll
    for (int r = 0; r < 4; ++r) {
        int m = q*4 + r;
        float zn = (acc[r] - bnM[m]) * bnR[m] * pp[16+m] + pp[32+m];
        float rl = zn + h[r] * pp[m];
        tmp[r] = rl > 0.f ? rl : 0.f;
    }
    bn_stats1(tmp, bnS, bnQ, bnM, bnR, q, c, w, tid);
#pragma unroll
    for (int r = 0; r < 4; ++r) {
        int m = q*4 + r;
        h[r] = (tmp[r] - bnM[m]) * bnR[m] * pp[48+m] + pp[64+m];
    }
}

// write h (C/D layout) to exchange [K/8][B][8]packed-words via sc1 8B atomic stores
__device__ __forceinline__ void store_h1(unsigned* hp, const f32x4 h,
                                         int c0, int q, int c, int w) {
    unsigned long long* hpu = (unsigned long long*)hp;
    const int b = w*16 + c;
    const long long idx = (long long)(((c0 >> 3) + (q >> 1))*256 + b)*4 + (q & 1)*2;
    unsigned w0 = packhl(h[0]), w1 = packhl(h[1]), w2 = packhl(h[2]), w3 = packhl(h[3]);
    __hip_atomic_store(hpu + idx,     (unsigned long long)w0 | ((unsigned long long)w1 << 32),
                       __ATOMIC_RELAXED, __HIP_MEMORY_SCOPE_AGENT);
    __hip_atomic_store(hpu + idx + 1, (unsigned long long)w2 | ((unsigned long long)w3 << 32),
                       __ATOMIC_RELAXED, __HIP_MEMORY_SCOPE_AGENT);
}

// GEMM cell: z = hprev @ Wm^T from exchange buffer (B 32B/lane loads, A LDS)
__device__ __forceinline__ void cell_h1(const unsigned* __restrict__ hw,
                                        const unsigned short* waHi, const unsigned short* waLo,
                                        f32x4& h, const float* pp,
                                        float* bnS, float* bnQ, float* bnM, float* bnR,
                                        unsigned* hpdst, int c0, int q, int c, int w, int tid) {
    f32x4 acc = {};
    const unsigned* p = hw + (q*256 + w*16 + c)*8;
#pragma unroll
    for (int ks = 0; ks < 16; ++ks) {
        half8 ahi = *(const half8*)(waHi + ks*512);
        half8 alo = *(const half8*)(waLo + ks*512);
        mfma3p(p + ks*8192, ahi, alo, acc);
    }
    bn_tail1(acc, h, pp, bnS, bnQ, bnM, bnR, q, c, w, tid);
    if (hpdst) store_h1(hpdst, h, c0, q, c, w);
}

// cell0-lite: z0 precomputed -> one 16B load + unpack + BN tail
__device__ __forceinline__ void cell0lite(const unsigned* __restrict__ z0, int t,
                                          f32x4& h0, const float* pp,
                                          float* bnS, float* bnQ, float* bnM, float* bnR,
                                          unsigned* hpdst, int c0, int q, int c, int w, int tid) {
    const unsigned* zp = z0 + (long long)(w*16 + c)*131072LL + (long long)t*512 + c0 + q*4;
    uint4 zw = *(const uint4*)zp;
    f32x4 acc;
    acc[0] = unpackhl(zw.x); acc[1] = unpackhl(zw.y);
    acc[2] = unpackhl(zw.z); acc[3] = unpackhl(zw.w);
    bn_tail1(acc, h0, pp, bnS, bnQ, bnM, bnR, q, c, w, tid);
    store_h1(hpdst, h0, c0, q, c, w);
}

__global__ __launch_bounds__(BT, 4) void indrnn(
    const unsigned* __restrict__ z0,             // packed z0 (in x's buffer)
    const float* __restrict__ Wm,
    const float* __restrict__ u0,  const float* __restrict__ g10,
    const float* __restrict__ be10, const float* __restrict__ g20,
    const float* __restrict__ be20,
    const float* __restrict__ um,  const float* __restrict__ g1m,
    const float* __restrict__ be1m, const float* __restrict__ g2m,
    const float* __restrict__ be2m,
    const float* __restrict__ Wfc, const float* __restrict__ bfc,
    float* __restrict__ out, int* __restrict__ bar,
    unsigned* __restrict__ hpws,                 // hp0[2],hp1[2]: 4 x 131072 words
    float* __restrict__ h2n)                     // [256][512] fp32
{
    __shared__ __align__(16) unsigned short WAhi_m[8192];  // Wm A-frags hi (head reuses)
    __shared__ __align__(16) unsigned short WAlo_m[8192];
    __shared__ float bnS[256], bnQ[256], bnM[16], bnR[16];
    __shared__ float prm[160];

    const int tid  = threadIdx.x;
    const int blk  = blockIdx.x;
    const int lane = tid & 63;
    const int w    = tid >> 6;
    const int q    = lane >> 4;
    const int c    = lane & 15;
    const int c0   = blk * 16;

    // ---- stage Wm A-fragments into LDS, hi/lo planes (A[m=lane&15][k=q*8+j]) ----
    if (tid < 1024) {
        int e = tid;
        int ks = e >> 6, l = e & 63;
        int cc = l & 15, qq = l >> 4;
        const float* sm = Wm + (size_t)(c0 + cc)*512 + ks*32 + qq*8;
        unsigned short mh[8], ml[8];
#pragma unroll
        for (int j = 0; j < 8; ++j) {
            unsigned pm = packhl(sm[j]);
            mh[j] = (unsigned short)pm; ml[j] = (unsigned short)(pm >> 16);
        }
        __builtin_memcpy(&WAhi_m[e*8], mh, 16);
        __builtin_memcpy(&WAlo_m[e*8], ml, 16);
    }
    if (tid < 16) {
        prm[tid]      = u0[c0+tid];   prm[16+tid]  = g10[c0+tid];  prm[32+tid]  = be10[c0+tid];
        prm[48+tid]   = g20[c0+tid];  prm[64+tid]  = be20[c0+tid];
        prm[80+tid]   = um[c0+tid];   prm[96+tid]  = g1m[c0+tid];  prm[112+tid] = be1m[c0+tid];
        prm[128+tid]  = g2m[c0+tid];  prm[144+tid] = be2m[c0+tid];
    }
    __syncthreads();

    // ---- sequential recurrence: 256 steps, ONE grid barrier per step ----
    // schedule: cell1(t); cell0lite(t+1); barrier; cell2(t)  (parity dbuf)
    f32x4 h0 = {}, h1 = {}, h2 = {};
    const unsigned short* waHi = WAhi_m + lane*8;
    const unsigned short* waLo = WAlo_m + lane*8;

    cell0lite(z0, 0, h0, prm, bnS, bnQ, bnM, bnR, hpws, c0, q, c, w, tid);
    grid_barrier(bar, 0);

    for (int t = 0; t < kT; ++t) {
        const int par = t & 1;
        unsigned* hp0r = hpws + par*131072;
        unsigned* hp0w = hpws + (par^1)*131072;
        unsigned* hp1r = hpws + 262144 + par*131072;

        cell_h1(hp0r, waHi, waLo, h1, prm + 80, bnS, bnQ, bnM, bnR, hp1r, c0, q, c, w, tid);
        if (t + 1 < kT)
            cell0lite(z0, t + 1, h0, prm, bnS, bnQ, bnM, bnR, hp0w, c0, q, c, w, tid);
        grid_barrier(bar, 1 + t);
        cell_h1(hp1r, waHi, waLo, h2, prm + 80, bnS, bnQ, bnM, bnR, (unsigned*)nullptr,
                c0, q, c, w, tid);
    }

    // ---- final h2 -> h2n (fp32, sc1 8B stores) ----
    {
        unsigned long long* h2u = (unsigned long long*)h2n;
        const int b = w*16 + c;
#pragma unroll
        for (int pr = 0; pr < 2; ++pr) {
            float fv[2] = { h2[pr*2], h2[pr*2+1] };
            unsigned long long val;
            __builtin_memcpy(&val, fv, 8);
            __hip_atomic_store(h2u + (((size_t)b*512 + c0 + q*4) >> 1) + pr, val,
                               __ATOMIC_RELAXED, __HIP_MEMORY_SCOPE_AGENT);
        }
    }
    grid_barrier(bar, 1 + kT);

    // ---- head: 8 batch rows per block (waves 0..7), logits + log_softmax ----
    {
        float* hs = (float*)WAhi_m;   // reuse 16KB LDS: 8 rows x 512 fp32
        __syncthreads();
        ((float4*)hs)[tid] = ((const float4*)(h2n + (size_t)blk*4096))[tid];
        __syncthreads();
        if (w < 8) {
            const int row = w;
            const int o0  = lane * 4;
            const float* hrow = hs + row*512;
            float dots[4] = {bfc[o0], bfc[o0+1], bfc[o0+2], bfc[o0+3]};
#pragma unroll 4
            for (int h = 0; h < 512; h += 4) {
                float4 hv = *(const float4*)(hrow + h);
#pragma unroll
                for (int oo = 0; oo < 4; ++oo) {
                    float4 wv = *(const float4*)(Wfc + (size_t)(o0+oo)*512 + h);
                    dots[oo] += hv.x*wv.x + hv.y*wv.y + hv.z*wv.z + hv.w*wv.w;
                }
            }
            float M = fmaxf(fmaxf(dots[0], dots[1]), fmaxf(dots[2], dots[3]));
#pragma unroll
            for (int mk = 1; mk < 64; mk <<= 1) M = fmaxf(M, __shfl_xor(M, mk, 64));
            float S = 0.f;
#pragma unroll
            for (int oo = 0; oo < 4; ++oo) S += expf(dots[oo] - M);
#pragma unroll
            for (int mk = 1; mk < 64; mk <<= 1) S += __shfl_xor(S, mk, 64);
            float lse = M + logf(S);
#pragma unroll
            for (int oo = 0; oo < 4; ++oo)
                out[(size_t)(blk*8 + row)*256 + o0 + oo] = dots[oo] - lse;
        }
    }
}

extern "C" void kernel_launch(void* const* d_in, const int* in_sizes, int n_in,
                              void* d_out, int out_size, void* d_ws, size_t ws_size,
                              hipStream_t stream) {
    float* x          = (float*)d_in[0];          // mutated; harness restores pristine
    const float* W0   = (const float*)d_in[1];
    const float* u0   = (const float*)d_in[3];
    const float* g10  = (const float*)d_in[4];
    const float* be10 = (const float*)d_in[5];
    const float* g20  = (const float*)d_in[6];
    const float* be20 = (const float*)d_in[7];
    const float* Wm   = (const float*)d_in[8];
    const float* um   = (const float*)d_in[10];
    const float* g1m  = (const float*)d_in[11];
    const float* be1m = (const float*)d_in[12];
    const float* g2m  = (const float*)d_in[13];
    const float* be2m = (const float*)d_in[14];
    const float* Wfc  = (const float*)d_in[15];
    const float* bfc  = (const float*)d_in[16];
    // b0 (d_in[2]) / bm (d_in[9]) cancel inside training-mode BatchNorm -> unused
    float* out = (float*)d_out;

    char* ws = (char*)d_ws;
    int* bar        = (int*)ws;                            // 128KB barrier phases
    unsigned* hpws  = (unsigned*)(ws + 131072);            // 4 x 512KB h exchange
    float* h2n      = (float*)(ws + 131072 + 2097152);     // 512KB
    unsigned* W0p   = (unsigned*)(ws + 131072 + 2621440);  // 1MB packed W0

    hipMemsetAsync(bar, 0, BARBYTES, stream);
    hipLaunchKernelGGL(w0pack, dim3(256), dim3(256), 0, stream, W0, W0p);
    hipLaunchKernelGGL(zgemm, dim3(2048), dim3(1024), 0, stream, x, W0p);
    hipLaunchKernelGGL(indrnn, dim3(NB), dim3(BT), 0, stream,
                       (const unsigned*)x, Wm, u0, g10, be10, g20, be20,
                       um, g1m, be1m, g2m, be2m, Wfc, bfc,
                       out, bar, hpws, h2n);
}